// Round 4
// baseline (116.156 us; speedup 1.0000x reference)
//
#include <hip/hip_runtime.h>
#include <stdint.h>

#define BATCH   1024
#define IDIM    4096
#define NLUTS   16384

// ---- main kernel geometry ----
#define TPB     1024
#define NT      2                  // n's per thread
#define NPB     (TPB * NT)         // 2048
#define NBLK_N  (NLUTS / NPB)      // 8
#define BT      4                  // batch rows per tile -> ds_read_b128 gather
#define TILES   4                  // tiles per block
#define ROWS    (BT * TILES)       // 16 rows per block
#define NBLK_B  (BATCH / ROWS)     // 64
#define GRID    (NBLK_N * NBLK_B)  // 512  (= 2 blocks per CU exactly)

// ---------------- coefficient pre-kernel ----------------
// a[n][mask]: monomial coefficients of the multilinear form, from
// s = sigmoid(w - wc) reversed + 4-level butterfly (p0,p1)->(p1,p0-p1).
__global__ void coeff_kernel(const float* __restrict__ w,
                             const float* __restrict__ wc,
                             float* __restrict__ cf)
{
    int n = blockIdx.x * 64 + threadIdx.x;   // grid = 256 x 64
    float p[16];
#pragma unroll
    for (int k = 0; k < 4; ++k) {
        float4 wv = *reinterpret_cast<const float4*>(w  + (size_t)n * 16 + 4 * k);
        float4 cv = *reinterpret_cast<const float4*>(wc + (size_t)n * 16 + 4 * k);
        p[15 - (4 * k + 0)] = 1.f / (1.f + __expf(cv.x - wv.x));
        p[15 - (4 * k + 1)] = 1.f / (1.f + __expf(cv.y - wv.y));
        p[15 - (4 * k + 2)] = 1.f / (1.f + __expf(cv.z - wv.z));
        p[15 - (4 * k + 3)] = 1.f / (1.f + __expf(cv.w - wv.w));
    }
#pragma unroll
    for (int s = 8; s >= 1; s >>= 1) {
#pragma unroll
        for (int m = 0; m < 16; ++m) {
            if ((m & s) == 0) { float t0 = p[m]; p[m] = p[m + s]; p[m + s] = t0 - p[m + s]; }
        }
    }
#pragma unroll
    for (int k = 0; k < 4; ++k) {
        float4 o; o.x = p[4*k]; o.y = p[4*k+1]; o.z = p[4*k+2]; o.w = p[4*k+3];
        *reinterpret_cast<float4*>(cf + (size_t)n * 16 + 4 * k) = o;
    }
}

// ---------------- main kernel ----------------
__global__ __launch_bounds__(TPB, 8)   // 8 waves/EU -> 2x1024t blocks/CU, VGPR<=64
void lut_main(const float* __restrict__ x,
              const float* __restrict__ cf,
              const int*   __restrict__ indices,
              float* __restrict__ out)
{
    // transposed tile: xt[col*4 + r] holds x[brow + r][col]. 64 KB, single buf.
    __shared__ float xt[IDIM * BT];

    // XCD swizzle: per XCD, n_blk varies fastest -> the 8 blocks sharing a
    // b-range run back-to-back on one XCD; 8 b-ranges x 16 rows x 16KB = 2 MiB
    // of x stays L2-resident per XCD.
    int id    = blockIdx.x;
    int xcd   = id & 7;
    int k     = id >> 3;                 // 0..63
    int n_blk = k & (NBLK_N - 1);        // 0..7, fastest
    int b_blk = (k >> 3) * 8 + xcd;      // 0..63, bijective
    int t     = threadIdx.x;
    int n0    = n_blk * NPB + t * NT;
    int b0    = b_blk * ROWS;

    // per-thread LUT indices: ix[q][i] = indices[i][n0+q]
    int ix[NT][4];
#pragma unroll
    for (int i = 0; i < 4; ++i) {
        int2 v = *reinterpret_cast<const int2*>(indices + i * NLUTS + n0);
        ix[0][i] = v.x; ix[1][i] = v.y;
    }

    // per-thread monomial coefficients (precomputed, 1 MiB, L2-hot)
    float a[NT][16];
#pragma unroll
    for (int q = 0; q < NT; ++q) {
#pragma unroll
        for (int kk = 0; kk < 4; ++kk) {
            float4 v = *reinterpret_cast<const float4*>(cf + (size_t)(n0 + q) * 16 + 4 * kk);
            a[q][4*kk] = v.x; a[q][4*kk+1] = v.y; a[q][4*kk+2] = v.z; a[q][4*kk+3] = v.w;
        }
    }

    // staging: thread owns cols c = t + 1024*h, h=0..3; 4 rows each.
    // Global: lanes consecutive -> 256B coalesced. LDS write: ds_write_b128 at
    // col*16B, cols consecutive across the wave -> conflict-free.
    float st[16];

    auto load_tile = [&](int g) {
        const float* xb = x + (size_t)(b0 + g * BT) * IDIM;
#pragma unroll
        for (int h = 0; h < 4; ++h) {
#pragma unroll
            for (int r = 0; r < 4; ++r)
                st[h * 4 + r] = xb[(size_t)r * IDIM + h * TPB + t];
        }
    };
    auto write_tile = [&]() {
#pragma unroll
        for (int h = 0; h < 4; ++h) {
            float4 v; v.x = st[h*4+0]; v.y = st[h*4+1]; v.z = st[h*4+2]; v.w = st[h*4+3];
            *reinterpret_cast<float4*>(&xt[(h * TPB + t) * 4]) = v;
        }
    };

    load_tile(0);
    write_tile();
    __syncthreads();

#pragma unroll
    for (int g = 0; g < TILES; ++g) {
        if (g + 1 < TILES) load_tile(g + 1);   // prefetch next tile into regs

        // compute: per q, 4 b128 gathers (one per LUT input, 4 rows each)
        float res[NT][BT];
#pragma unroll
        for (int q = 0; q < NT; ++q) {
            float c[4][4];
#pragma unroll
            for (int i = 0; i < 4; ++i) {
                float4 v = *reinterpret_cast<const float4*>(&xt[ix[q][i] * 4]);
                c[i][0] = v.x; c[i][1] = v.y; c[i][2] = v.z; c[i][3] = v.w;
            }
#pragma unroll
            for (int r = 0; r < BT; ++r) {
                float v0 = c[0][r], v1 = c[1][r], v2 = c[2][r], v3 = c[3][r];
                float h0 = fmaf(v3, a[q][1],  a[q][0]);
                float h1 = fmaf(v3, a[q][3],  a[q][2]);
                float h2 = fmaf(v3, a[q][5],  a[q][4]);
                float h3 = fmaf(v3, a[q][7],  a[q][6]);
                float h4 = fmaf(v3, a[q][9],  a[q][8]);
                float h5 = fmaf(v3, a[q][11], a[q][10]);
                float h6 = fmaf(v3, a[q][13], a[q][12]);
                float h7 = fmaf(v3, a[q][15], a[q][14]);
                float g0 = fmaf(v2, h1, h0);
                float g1 = fmaf(v2, h3, h2);
                float g2 = fmaf(v2, h5, h4);
                float g3 = fmaf(v2, h7, h6);
                float f0 = fmaf(v1, g1, g0);
                float f1 = fmaf(v1, g3, g2);
                res[q][r] = fmaf(v0, f1, f0);
            }
        }

        // coalesced float2 stores: 4 rows x (2 consecutive n per thread)
#pragma unroll
        for (int r = 0; r < BT; ++r) {
            float2 o; o.x = res[0][r]; o.y = res[1][r];
            *reinterpret_cast<float2*>(out + (size_t)(b0 + g * BT + r) * NLUTS + n0) = o;
        }

        __syncthreads();                       // all reads of xt done
        if (g + 1 < TILES) {
            write_tile();                      // overwrite with prefetched tile
            __syncthreads();
        }
    }
}

// ---------------- fallback (round-1 fused kernel, used only if ws too small) ----------------
#define F_TPB   256
#define F_NT    4
#define F_NPB   (F_TPB * F_NT)
#define F_NBLKN (NLUTS / F_NPB)
#define F_BTILE 16
#define F_GRID  (F_NBLKN * (BATCH / F_BTILE))

__global__ __launch_bounds__(F_TPB, 4)
void lut_fused(const float* __restrict__ x, const float* __restrict__ w,
               const float* __restrict__ wcomp, const int* __restrict__ indices,
               float* __restrict__ out)
{
    __shared__ float xsf[2][IDIM];
    int id = blockIdx.x;
    int swz = (id & 7) * (F_GRID / 8) + (id >> 3);
    int b_blk = swz / F_NBLKN, n_blk = swz % F_NBLKN;
    int t = threadIdx.x;
    int n0 = n_blk * F_NPB + t * F_NT;
    int b0 = b_blk * F_BTILE;
    int ix[F_NT][4];
#pragma unroll
    for (int i = 0; i < 4; ++i) {
        int4 v = *reinterpret_cast<const int4*>(indices + i * NLUTS + n0);
        ix[0][i] = v.x; ix[1][i] = v.y; ix[2][i] = v.z; ix[3][i] = v.w;
    }
    float a[F_NT][16];
#pragma unroll
    for (int q = 0; q < F_NT; ++q) {
        int n = n0 + q; float p[16];
#pragma unroll
        for (int k = 0; k < 4; ++k) {
            float4 wv = *reinterpret_cast<const float4*>(w     + (size_t)n * 16 + k * 4);
            float4 cv = *reinterpret_cast<const float4*>(wcomp + (size_t)n * 16 + k * 4);
            p[15-(4*k+0)] = 1.f/(1.f+__expf(cv.x-wv.x));
            p[15-(4*k+1)] = 1.f/(1.f+__expf(cv.y-wv.y));
            p[15-(4*k+2)] = 1.f/(1.f+__expf(cv.z-wv.z));
            p[15-(4*k+3)] = 1.f/(1.f+__expf(cv.w-wv.w));
        }
#pragma unroll
        for (int s = 8; s >= 1; s >>= 1)
#pragma unroll
            for (int m = 0; m < 16; ++m)
                if ((m & s) == 0) { float t0 = p[m]; p[m] = p[m+s]; p[m+s] = t0 - p[m+s]; }
#pragma unroll
        for (int m = 0; m < 16; ++m) a[q][m] = p[m];
    }
    {
        const float* xrow = x + (size_t)b0 * IDIM;
#pragma unroll
        for (int k = 0; k < 4; ++k)
            *reinterpret_cast<float4*>(&xsf[0][(k*F_TPB+t)*4]) =
                *reinterpret_cast<const float4*>(xrow + (k*F_TPB+t)*4);
    }
    __syncthreads();
    for (int bi = 0; bi < F_BTILE; ++bi) {
        int cur = bi & 1; bool more = (bi + 1 < F_BTILE);
        float4 r[4];
        if (more) {
            const float* xrow = x + (size_t)(b0+bi+1) * IDIM;
#pragma unroll
            for (int k = 0; k < 4; ++k)
                r[k] = *reinterpret_cast<const float4*>(xrow + (k*F_TPB+t)*4);
        }
        float res[F_NT];
#pragma unroll
        for (int q = 0; q < F_NT; ++q) {
            float v0 = xsf[cur][ix[q][0]], v1 = xsf[cur][ix[q][1]];
            float v2 = xsf[cur][ix[q][2]], v3 = xsf[cur][ix[q][3]];
            float h0 = fmaf(v3,a[q][1],a[q][0]),  h1 = fmaf(v3,a[q][3],a[q][2]);
            float h2 = fmaf(v3,a[q][5],a[q][4]),  h3 = fmaf(v3,a[q][7],a[q][6]);
            float h4 = fmaf(v3,a[q][9],a[q][8]),  h5 = fmaf(v3,a[q][11],a[q][10]);
            float h6 = fmaf(v3,a[q][13],a[q][12]),h7 = fmaf(v3,a[q][15],a[q][14]);
            float g0 = fmaf(v2,h1,h0), g1 = fmaf(v2,h3,h2);
            float g2 = fmaf(v2,h5,h4), g3 = fmaf(v2,h7,h6);
            res[q] = fmaf(v0, fmaf(v1,g3,g2), fmaf(v1,g1,g0));
        }
        float4 o; o.x=res[0]; o.y=res[1]; o.z=res[2]; o.w=res[3];
        *reinterpret_cast<float4*>(out + (size_t)(b0+bi)*NLUTS + n0) = o;
        if (more) {
            int nxt = cur ^ 1;
#pragma unroll
            for (int k = 0; k < 4; ++k)
                *reinterpret_cast<float4*>(&xsf[nxt][(k*F_TPB+t)*4]) = r[k];
        }
        __syncthreads();
    }
}

extern "C" void kernel_launch(void* const* d_in, const int* in_sizes, int n_in,
                              void* d_out, int out_size, void* d_ws, size_t ws_size,
                              hipStream_t stream) {
    const float* x   = (const float*)d_in[0];
    const float* w   = (const float*)d_in[1];
    const float* wc  = (const float*)d_in[2];
    const int*   idx = (const int*)d_in[3];
    float*       out = (float*)d_out;

    if (ws_size >= (size_t)NLUTS * 16 * sizeof(float)) {
        float* cf = (float*)d_ws;
        coeff_kernel<<<dim3(NLUTS / 64), dim3(64), 0, stream>>>(w, wc, cf);
        lut_main<<<dim3(GRID), dim3(TPB), 0, stream>>>(x, cf, idx, out);
    } else {
        lut_fused<<<dim3(F_GRID), dim3(F_TPB), 0, stream>>>(x, w, wc, idx, out);
    }
}

// Round 5
// 51.151 us; speedup vs baseline: 2.2709x; 2.2709x over previous
//
#include <hip/hip_runtime.h>
#include <hip/hip_fp16.h>
#include <stdint.h>

#define BATCH   1024
#define IDIM    4096
#define NLUTS   16384

// ---- main kernel geometry ----
#define TPB     512
#define NT      2                  // n's per thread
#define NPB     (TPB * NT)         // 1024
#define NBLK_N  (NLUTS / NPB)      // 16
#define BT      4                  // batch rows per tile (fp16 -> ds_read_b64 gather)
#define TILES   4                  // tiles per block
#define ROWS    (BT * TILES)       // 16 rows per block
#define NBLK_B  (BATCH / ROWS)     // 64
#define GRID    (NBLK_N * NBLK_B)  // 1024 = 4 blocks/CU exactly (whole grid resident)

// ---------------- coefficient pre-kernel ----------------
// a[n][mask]: monomial coefficients of the multilinear form, from
// s = sigmoid(w - wc) reversed + 4-level butterfly (p0,p1)->(p1,p0-p1).
__global__ void coeff_kernel(const float* __restrict__ w,
                             const float* __restrict__ wc,
                             float* __restrict__ cf)
{
    int n = blockIdx.x * 64 + threadIdx.x;   // grid = 256 x 64
    float p[16];
#pragma unroll
    for (int k = 0; k < 4; ++k) {
        float4 wv = *reinterpret_cast<const float4*>(w  + (size_t)n * 16 + 4 * k);
        float4 cv = *reinterpret_cast<const float4*>(wc + (size_t)n * 16 + 4 * k);
        p[15 - (4 * k + 0)] = 1.f / (1.f + __expf(cv.x - wv.x));
        p[15 - (4 * k + 1)] = 1.f / (1.f + __expf(cv.y - wv.y));
        p[15 - (4 * k + 2)] = 1.f / (1.f + __expf(cv.z - wv.z));
        p[15 - (4 * k + 3)] = 1.f / (1.f + __expf(cv.w - wv.w));
    }
#pragma unroll
    for (int s = 8; s >= 1; s >>= 1) {
#pragma unroll
        for (int m = 0; m < 16; ++m) {
            if ((m & s) == 0) { float t0 = p[m]; p[m] = p[m + s]; p[m + s] = t0 - p[m + s]; }
        }
    }
#pragma unroll
    for (int k = 0; k < 4; ++k) {
        float4 o; o.x = p[4*k]; o.y = p[4*k+1]; o.z = p[4*k+2]; o.w = p[4*k+3];
        *reinterpret_cast<float4*>(cf + (size_t)n * 16 + 4 * k) = o;
    }
}

// ---------------- main kernel ----------------
// fp16 LDS tile: 32 KB -> 4 blocks/CU x 8 waves = 32 waves/CU at VGPR<=64.
__global__ __launch_bounds__(TPB, 8)
void lut_main(const float* __restrict__ x,
              const float* __restrict__ cf,
              const int*   __restrict__ indices,
              float* __restrict__ out)
{
    // transposed fp16 tile: xt[col*4 + r] = x[brow+r][col]. 32 KB.
    __shared__ __half xt[IDIM * BT];

    // XCD swizzle: per XCD the 16 n-blocks of one b-range are consecutive
    // (and, at 4 blocks/CU, ALL simultaneously resident) -> x rows staged
    // from that XCD's L2, out writes XCD-local.
    int id    = blockIdx.x;
    int xcd   = id & 7;
    int k     = id >> 3;                 // 0..127
    int n_blk = k & (NBLK_N - 1);        // 0..15, fastest
    int b_blk = (k >> 4) * 8 + xcd;      // 0..63, bijective
    int t     = threadIdx.x;
    int n0    = n_blk * NPB + t * NT;
    int b0    = b_blk * ROWS;

    // per-thread LUT indices -> LDS byte offsets (ix*8B per column)
    uint32_t off[NT][4];
#pragma unroll
    for (int i = 0; i < 4; ++i) {
        int2 v = *reinterpret_cast<const int2*>(indices + i * NLUTS + n0);
        off[0][i] = (uint32_t)v.x * 8u;
        off[1][i] = (uint32_t)v.y * 8u;
    }

    // per-thread monomial coefficients (precomputed, 1 MiB, L2-hot)
    float a[NT][16];
#pragma unroll
    for (int q = 0; q < NT; ++q) {
#pragma unroll
        for (int kk = 0; kk < 4; ++kk) {
            float4 v = *reinterpret_cast<const float4*>(cf + (size_t)(n0 + q) * 16 + 4 * kk);
            a[q][4*kk] = v.x; a[q][4*kk+1] = v.y; a[q][4*kk+2] = v.z; a[q][4*kk+3] = v.w;
        }
    }

    const char* xt_bytes = reinterpret_cast<const char*>(xt);

#pragma unroll 1
    for (int g = 0; g < TILES; ++g) {
        if (g) __syncthreads();            // previous tile's reads complete

        // ---- stage tile g: thread owns col pairs p = t + 512*h, h=0..3 ----
        // global: float2 loads, 512 lanes x 8B = 4KB contiguous per h,r.
        // LDS: one ds_write_b128 per pair at byte p*16 -> lanes 0..7 cover all
        // 32 banks exactly once -> conflict-free.
        {
            const float* xb = x + (size_t)(b0 + g * BT) * IDIM;
#pragma unroll
            for (int h = 0; h < 4; ++h) {
                int p = h * TPB + t;
                int c = 2 * p;
                float2 r0 = *reinterpret_cast<const float2*>(xb + 0 * IDIM + c);
                float2 r1 = *reinterpret_cast<const float2*>(xb + 1 * IDIM + c);
                float2 r2 = *reinterpret_cast<const float2*>(xb + 2 * IDIM + c);
                float2 r3 = *reinterpret_cast<const float2*>(xb + 3 * IDIM + c);
                __half2 c0a = __floats2half2_rn(r0.x, r1.x);   // col c rows 0,1
                __half2 c0b = __floats2half2_rn(r2.x, r3.x);   // col c rows 2,3
                __half2 c1a = __floats2half2_rn(r0.y, r1.y);   // col c+1 rows 0,1
                __half2 c1b = __floats2half2_rn(r2.y, r3.y);   // col c+1 rows 2,3
                uint4 v;
                v.x = *reinterpret_cast<uint32_t*>(&c0a);
                v.y = *reinterpret_cast<uint32_t*>(&c0b);
                v.z = *reinterpret_cast<uint32_t*>(&c1a);
                v.w = *reinterpret_cast<uint32_t*>(&c1b);
                *reinterpret_cast<uint4*>(&xt[(size_t)c * 4]) = v;
            }
        }
        __syncthreads();                   // tile visible to all waves

        // ---- compute: per q, 4 x ds_read_b64 gathers (4 rows each) ----
        float res[NT][BT];
#pragma unroll
        for (int q = 0; q < NT; ++q) {
#pragma unroll
            for (int r = 0; r < BT; ++r) res[q][r] = 0.f;
            uint2 gld[4];
#pragma unroll
            for (int i = 0; i < 4; ++i)
                gld[i] = *reinterpret_cast<const uint2*>(xt_bytes + off[q][i]);
#pragma unroll
            for (int r = 0; r < BT; ++r) {
                // unpack row r of each of the 4 gathered columns
                float v0, v1, v2, v3;
                {
                    __half2 h01 = *reinterpret_cast<__half2*>(&gld[0].x);
                    __half2 h23 = *reinterpret_cast<__half2*>(&gld[0].y);
                    float2 f01 = __half22float2(h01), f23 = __half22float2(h23);
                    v0 = (r == 0) ? f01.x : (r == 1) ? f01.y : (r == 2) ? f23.x : f23.y;
                }
                {
                    __half2 h01 = *reinterpret_cast<__half2*>(&gld[1].x);
                    __half2 h23 = *reinterpret_cast<__half2*>(&gld[1].y);
                    float2 f01 = __half22float2(h01), f23 = __half22float2(h23);
                    v1 = (r == 0) ? f01.x : (r == 1) ? f01.y : (r == 2) ? f23.x : f23.y;
                }
                {
                    __half2 h01 = *reinterpret_cast<__half2*>(&gld[2].x);
                    __half2 h23 = *reinterpret_cast<__half2*>(&gld[2].y);
                    float2 f01 = __half22float2(h01), f23 = __half22float2(h23);
                    v2 = (r == 0) ? f01.x : (r == 1) ? f01.y : (r == 2) ? f23.x : f23.y;
                }
                {
                    __half2 h01 = *reinterpret_cast<__half2*>(&gld[3].x);
                    __half2 h23 = *reinterpret_cast<__half2*>(&gld[3].y);
                    float2 f01 = __half22float2(h01), f23 = __half22float2(h23);
                    v3 = (r == 0) ? f01.x : (r == 1) ? f01.y : (r == 2) ? f23.x : f23.y;
                }
                float h0 = fmaf(v3, a[q][1],  a[q][0]);
                float h1 = fmaf(v3, a[q][3],  a[q][2]);
                float h2 = fmaf(v3, a[q][5],  a[q][4]);
                float h3 = fmaf(v3, a[q][7],  a[q][6]);
                float h4 = fmaf(v3, a[q][9],  a[q][8]);
                float h5 = fmaf(v3, a[q][11], a[q][10]);
                float h6 = fmaf(v3, a[q][13], a[q][12]);
                float h7 = fmaf(v3, a[q][15], a[q][14]);
                float g0 = fmaf(v2, h1, h0);
                float g1 = fmaf(v2, h3, h2);
                float g2 = fmaf(v2, h5, h4);
                float g3 = fmaf(v2, h7, h6);
                float f0 = fmaf(v1, g1, g0);
                float f1 = fmaf(v1, g3, g2);
                res[q][r] = fmaf(v0, f1, f0);
            }
        }

        // coalesced float2 stores: 4 rows x (2 consecutive n per thread)
#pragma unroll
        for (int r = 0; r < BT; ++r) {
            float2 o; o.x = res[0][r]; o.y = res[1][r];
            *reinterpret_cast<float2*>(out + (size_t)(b0 + g * BT + r) * NLUTS + n0) = o;
        }
    }
}

// ---------------- fallback (round-1 fused kernel, used only if ws too small) ----------------
#define F_TPB   256
#define F_NT    4
#define F_NPB   (F_TPB * F_NT)
#define F_NBLKN (NLUTS / F_NPB)
#define F_BTILE 16
#define F_GRID  (F_NBLKN * (BATCH / F_BTILE))

__global__ __launch_bounds__(F_TPB, 4)
void lut_fused(const float* __restrict__ x, const float* __restrict__ w,
               const float* __restrict__ wcomp, const int* __restrict__ indices,
               float* __restrict__ out)
{
    __shared__ float xsf[2][IDIM];
    int id = blockIdx.x;
    int swz = (id & 7) * (F_GRID / 8) + (id >> 3);
    int b_blk = swz / F_NBLKN, n_blk = swz % F_NBLKN;
    int t = threadIdx.x;
    int n0 = n_blk * F_NPB + t * F_NT;
    int b0 = b_blk * F_BTILE;
    int ix[F_NT][4];
#pragma unroll
    for (int i = 0; i < 4; ++i) {
        int4 v = *reinterpret_cast<const int4*>(indices + i * NLUTS + n0);
        ix[0][i] = v.x; ix[1][i] = v.y; ix[2][i] = v.z; ix[3][i] = v.w;
    }
    float a[F_NT][16];
#pragma unroll
    for (int q = 0; q < F_NT; ++q) {
        int n = n0 + q; float p[16];
#pragma unroll
        for (int k = 0; k < 4; ++k) {
            float4 wv = *reinterpret_cast<const float4*>(w     + (size_t)n * 16 + k * 4);
            float4 cv = *reinterpret_cast<const float4*>(wcomp + (size_t)n * 16 + k * 4);
            p[15-(4*k+0)] = 1.f/(1.f+__expf(cv.x-wv.x));
            p[15-(4*k+1)] = 1.f/(1.f+__expf(cv.y-wv.y));
            p[15-(4*k+2)] = 1.f/(1.f+__expf(cv.z-wv.z));
            p[15-(4*k+3)] = 1.f/(1.f+__expf(cv.w-wv.w));
        }
#pragma unroll
        for (int s = 8; s >= 1; s >>= 1)
#pragma unroll
            for (int m = 0; m < 16; ++m)
                if ((m & s) == 0) { float t0 = p[m]; p[m] = p[m+s]; p[m+s] = t0 - p[m+s]; }
#pragma unroll
        for (int m = 0; m < 16; ++m) a[q][m] = p[m];
    }
    {
        const float* xrow = x + (size_t)b0 * IDIM;
#pragma unroll
        for (int k = 0; k < 4; ++k)
            *reinterpret_cast<float4*>(&xsf[0][(k*F_TPB+t)*4]) =
                *reinterpret_cast<const float4*>(xrow + (k*F_TPB+t)*4);
    }
    __syncthreads();
    for (int bi = 0; bi < F_BTILE; ++bi) {
        int cur = bi & 1; bool more = (bi + 1 < F_BTILE);
        float4 r[4];
        if (more) {
            const float* xrow = x + (size_t)(b0+bi+1) * IDIM;
#pragma unroll
            for (int k = 0; k < 4; ++k)
                r[k] = *reinterpret_cast<const float4*>(xrow + (k*F_TPB+t)*4);
        }
        float res[F_NT];
#pragma unroll
        for (int q = 0; q < F_NT; ++q) {
            float v0 = xsf[cur][ix[q][0]], v1 = xsf[cur][ix[q][1]];
            float v2 = xsf[cur][ix[q][2]], v3 = xsf[cur][ix[q][3]];
            float h0 = fmaf(v3,a[q][1],a[q][0]),  h1 = fmaf(v3,a[q][3],a[q][2]);
            float h2 = fmaf(v3,a[q][5],a[q][4]),  h3 = fmaf(v3,a[q][7],a[q][6]);
            float h4 = fmaf(v3,a[q][9],a[q][8]),  h5 = fmaf(v3,a[q][11],a[q][10]);
            float h6 = fmaf(v3,a[q][13],a[q][12]),h7 = fmaf(v3,a[q][15],a[q][14]);
            float g0 = fmaf(v2,h1,h0), g1 = fmaf(v2,h3,h2);
            float g2 = fmaf(v2,h5,h4), g3 = fmaf(v2,h7,h6);
            res[q] = fmaf(v0, fmaf(v1,g3,g2), fmaf(v1,g1,g0));
        }
        float4 o; o.x=res[0]; o.y=res[1]; o.z=res[2]; o.w=res[3];
        *reinterpret_cast<float4*>(out + (size_t)(b0+bi)*NLUTS + n0) = o;
        if (more) {
            int nxt = cur ^ 1;
#pragma unroll
            for (int k = 0; k < 4; ++k)
                *reinterpret_cast<float4*>(&xsf[nxt][(k*F_TPB+t)*4]) = r[k];
        }
        __syncthreads();
    }
}

extern "C" void kernel_launch(void* const* d_in, const int* in_sizes, int n_in,
                              void* d_out, int out_size, void* d_ws, size_t ws_size,
                              hipStream_t stream) {
    const float* x   = (const float*)d_in[0];
    const float* w   = (const float*)d_in[1];
    const float* wc  = (const float*)d_in[2];
    const int*   idx = (const int*)d_in[3];
    float*       out = (float*)d_out;

    if (ws_size >= (size_t)NLUTS * 16 * sizeof(float)) {
        float* cf = (float*)d_ws;
        coeff_kernel<<<dim3(NLUTS / 64), dim3(64), 0, stream>>>(w, wc, cf);
        lut_main<<<dim3(GRID), dim3(TPB), 0, stream>>>(x, cf, idx, out);
    } else {
        lut_fused<<<dim3(F_GRID), dim3(F_TPB), 0, stream>>>(x, w, wc, idx, out);
    }
}

// Round 6
// 41.562 us; speedup vs baseline: 2.7948x; 1.2307x over previous
//
#include <hip/hip_runtime.h>
#include <hip/hip_fp16.h>
#include <stdint.h>

#define BATCH   1024
#define IDIM    4096
#define NLUTS   16384

// ---- main kernel geometry ----
#define TPB     512
#define NT      2                  // n's per thread
#define NPB     (TPB * NT)         // 1024
#define NBLK_N  (NLUTS / NPB)      // 16
#define BT      4                  // batch rows per tile (fp16 -> ds_read_b64 gather)
#define TILES   4                  // tiles per block
#define ROWS    (BT * TILES)       // 16 rows per block
#define NBLK_B  (BATCH / ROWS)     // 64
#define GRID    (NBLK_N * NBLK_B)  // 1024 = 4 blocks/CU exactly (whole grid resident)

// ---------------- coefficient pre-kernel ----------------
// a[n][mask]: monomial coefficients of the multilinear form, from
// s = sigmoid(w - wc) reversed + 4-level butterfly (p0,p1)->(p1,p0-p1).
__global__ void coeff_kernel(const float* __restrict__ w,
                             const float* __restrict__ wc,
                             float* __restrict__ cf)
{
    int n = blockIdx.x * 64 + threadIdx.x;   // grid = 256 x 64
    float p[16];
#pragma unroll
    for (int k = 0; k < 4; ++k) {
        float4 wv = *reinterpret_cast<const float4*>(w  + (size_t)n * 16 + 4 * k);
        float4 cv = *reinterpret_cast<const float4*>(wc + (size_t)n * 16 + 4 * k);
        p[15 - (4 * k + 0)] = 1.f / (1.f + __expf(cv.x - wv.x));
        p[15 - (4 * k + 1)] = 1.f / (1.f + __expf(cv.y - wv.y));
        p[15 - (4 * k + 2)] = 1.f / (1.f + __expf(cv.z - wv.z));
        p[15 - (4 * k + 3)] = 1.f / (1.f + __expf(cv.w - wv.w));
    }
#pragma unroll
    for (int s = 8; s >= 1; s >>= 1) {
#pragma unroll
        for (int m = 0; m < 16; ++m) {
            if ((m & s) == 0) { float t0 = p[m]; p[m] = p[m + s]; p[m + s] = t0 - p[m + s]; }
        }
    }
#pragma unroll
    for (int k = 0; k < 4; ++k) {
        float4 o; o.x = p[4*k]; o.y = p[4*k+1]; o.z = p[4*k+2]; o.w = p[4*k+3];
        *reinterpret_cast<float4*>(cf + (size_t)n * 16 + 4 * k) = o;
    }
}

// ---------------- main kernel ----------------
// fp16 LDS tile: 32 KB -> 4 blocks/CU x 8 waves = up to 32 waves/CU.
// launch_bounds(…, 4): empirically the ONLY setting that yields VGPR=64 with
// no scratch on this toolchain (",8" squeezes to 32 VGPR and spills — R4/R5).
__global__ __launch_bounds__(TPB, 4)
void lut_main(const float* __restrict__ x,
              const float* __restrict__ cf,
              const int*   __restrict__ indices,
              float* __restrict__ out)
{
    // transposed fp16 tile: xt[col*4 + r] = x[brow+r][col]. 32 KB.
    __shared__ __half xt[IDIM * BT];

    // XCD swizzle: per XCD the 16 n-blocks of one b-range are consecutive
    // (and, at 4 blocks/CU, simultaneously resident) -> x rows staged from
    // that XCD's L2, out writes XCD-local.
    int id    = blockIdx.x;
    int xcd   = id & 7;
    int k     = id >> 3;                 // 0..127
    int n_blk = k & (NBLK_N - 1);        // 0..15, fastest
    int b_blk = (k >> 4) * 8 + xcd;      // 0..63, bijective
    int t     = threadIdx.x;
    int n0    = n_blk * NPB + t * NT;
    int b0    = b_blk * ROWS;

    // per-thread LUT indices -> LDS byte offsets (ix*8B per column)
    uint32_t off[NT][4];
#pragma unroll
    for (int i = 0; i < 4; ++i) {
        int2 v = *reinterpret_cast<const int2*>(indices + i * NLUTS + n0);
        off[0][i] = (uint32_t)v.x * 8u;
        off[1][i] = (uint32_t)v.y * 8u;
    }

    // per-thread monomial coefficients (precomputed, 1 MiB, L2-hot)
    float a[NT][16];
#pragma unroll
    for (int q = 0; q < NT; ++q) {
#pragma unroll
        for (int kk = 0; kk < 4; ++kk) {
            float4 v = *reinterpret_cast<const float4*>(cf + (size_t)(n0 + q) * 16 + 4 * kk);
            a[q][4*kk] = v.x; a[q][4*kk+1] = v.y; a[q][4*kk+2] = v.z; a[q][4*kk+3] = v.w;
        }
    }

    const char* xt_bytes = reinterpret_cast<const char*>(xt);

#pragma unroll 1
    for (int g = 0; g < TILES; ++g) {
        if (g) __syncthreads();            // previous tile's reads complete

        // ---- stage tile g: thread owns col pairs p = t + 512*h, h=0..3 ----
        // global: float2 loads, 512 lanes x 8B contiguous per (h,row).
        // LDS: ds_write_b128 at byte p*16 -> consecutive lanes cover all 32
        // banks -> conflict-free.
        {
            const float* xb = x + (size_t)(b0 + g * BT) * IDIM;
#pragma unroll
            for (int h = 0; h < 4; ++h) {
                int p = h * TPB + t;
                int c = 2 * p;
                float2 r0 = *reinterpret_cast<const float2*>(xb + 0 * IDIM + c);
                float2 r1 = *reinterpret_cast<const float2*>(xb + 1 * IDIM + c);
                float2 r2 = *reinterpret_cast<const float2*>(xb + 2 * IDIM + c);
                float2 r3 = *reinterpret_cast<const float2*>(xb + 3 * IDIM + c);
                __half2 c0a = __floats2half2_rn(r0.x, r1.x);   // col c   rows 0,1
                __half2 c0b = __floats2half2_rn(r2.x, r3.x);   // col c   rows 2,3
                __half2 c1a = __floats2half2_rn(r0.y, r1.y);   // col c+1 rows 0,1
                __half2 c1b = __floats2half2_rn(r2.y, r3.y);   // col c+1 rows 2,3
                uint4 v;
                v.x = *reinterpret_cast<uint32_t*>(&c0a);
                v.y = *reinterpret_cast<uint32_t*>(&c0b);
                v.z = *reinterpret_cast<uint32_t*>(&c1a);
                v.w = *reinterpret_cast<uint32_t*>(&c1b);
                *reinterpret_cast<uint4*>(&xt[(size_t)c * 4]) = v;
            }
        }
        __syncthreads();                   // tile visible to all waves

        // ---- compute: per q, 4 x ds_read_b64 gathers (4 rows each) ----
        float res[NT][BT];
#pragma unroll
        for (int q = 0; q < NT; ++q) {
            uint2 gld[4];
#pragma unroll
            for (int i = 0; i < 4; ++i)
                gld[i] = *reinterpret_cast<const uint2*>(xt_bytes + off[q][i]);

            // convert each gathered column ONCE: c[i][r] = x[row r][col i]
            float c[4][4];
#pragma unroll
            for (int i = 0; i < 4; ++i) {
                __half2 h01 = *reinterpret_cast<__half2*>(&gld[i].x);
                __half2 h23 = *reinterpret_cast<__half2*>(&gld[i].y);
                float2 f01 = __half22float2(h01);
                float2 f23 = __half22float2(h23);
                c[i][0] = f01.x; c[i][1] = f01.y; c[i][2] = f23.x; c[i][3] = f23.y;
            }
#pragma unroll
            for (int r = 0; r < BT; ++r) {
                float v0 = c[0][r], v1 = c[1][r], v2 = c[2][r], v3 = c[3][r];
                float h0 = fmaf(v3, a[q][1],  a[q][0]);
                float h1 = fmaf(v3, a[q][3],  a[q][2]);
                float h2 = fmaf(v3, a[q][5],  a[q][4]);
                float h3 = fmaf(v3, a[q][7],  a[q][6]);
                float h4 = fmaf(v3, a[q][9],  a[q][8]);
                float h5 = fmaf(v3, a[q][11], a[q][10]);
                float h6 = fmaf(v3, a[q][13], a[q][12]);
                float h7 = fmaf(v3, a[q][15], a[q][14]);
                float g0 = fmaf(v2, h1, h0);
                float g1 = fmaf(v2, h3, h2);
                float g2 = fmaf(v2, h5, h4);
                float g3 = fmaf(v2, h7, h6);
                float f0 = fmaf(v1, g1, g0);
                float f1 = fmaf(v1, g3, g2);
                res[q][r] = fmaf(v0, f1, f0);
            }
        }

        // coalesced float2 stores: 4 rows x (2 consecutive n per thread)
#pragma unroll
        for (int r = 0; r < BT; ++r) {
            float2 o; o.x = res[0][r]; o.y = res[1][r];
            *reinterpret_cast<float2*>(out + (size_t)(b0 + g * BT + r) * NLUTS + n0) = o;
        }
    }
}

// ---------------- fallback (round-1 fused kernel, used only if ws too small) ----------------
#define F_TPB   256
#define F_NT    4
#define F_NPB   (F_TPB * F_NT)
#define F_NBLKN (NLUTS / F_NPB)
#define F_BTILE 16
#define F_GRID  (F_NBLKN * (BATCH / F_BTILE))

__global__ __launch_bounds__(F_TPB, 4)
void lut_fused(const float* __restrict__ x, const float* __restrict__ w,
               const float* __restrict__ wcomp, const int* __restrict__ indices,
               float* __restrict__ out)
{
    __shared__ float xsf[2][IDIM];
    int id = blockIdx.x;
    int swz = (id & 7) * (F_GRID / 8) + (id >> 3);
    int b_blk = swz / F_NBLKN, n_blk = swz % F_NBLKN;
    int t = threadIdx.x;
    int n0 = n_blk * F_NPB + t * F_NT;
    int b0 = b_blk * F_BTILE;
    int ix[F_NT][4];
#pragma unroll
    for (int i = 0; i < 4; ++i) {
        int4 v = *reinterpret_cast<const int4*>(indices + i * NLUTS + n0);
        ix[0][i] = v.x; ix[1][i] = v.y; ix[2][i] = v.z; ix[3][i] = v.w;
    }
    float a[F_NT][16];
#pragma unroll
    for (int q = 0; q < F_NT; ++q) {
        int n = n0 + q; float p[16];
#pragma unroll
        for (int k = 0; k < 4; ++k) {
            float4 wv = *reinterpret_cast<const float4*>(w     + (size_t)n * 16 + k * 4);
            float4 cv = *reinterpret_cast<const float4*>(wcomp + (size_t)n * 16 + k * 4);
            p[15-(4*k+0)] = 1.f/(1.f+__expf(cv.x-wv.x));
            p[15-(4*k+1)] = 1.f/(1.f+__expf(cv.y-wv.y));
            p[15-(4*k+2)] = 1.f/(1.f+__expf(cv.z-wv.z));
            p[15-(4*k+3)] = 1.f/(1.f+__expf(cv.w-wv.w));
        }
#pragma unroll
        for (int s = 8; s >= 1; s >>= 1)
#pragma unroll
            for (int m = 0; m < 16; ++m)
                if ((m & s) == 0) { float t0 = p[m]; p[m] = p[m+s]; p[m+s] = t0 - p[m+s]; }
#pragma unroll
        for (int m = 0; m < 16; ++m) a[q][m] = p[m];
    }
    {
        const float* xrow = x + (size_t)b0 * IDIM;
#pragma unroll
        for (int k = 0; k < 4; ++k)
            *reinterpret_cast<float4*>(&xsf[0][(k*F_TPB+t)*4]) =
                *reinterpret_cast<const float4*>(xrow + (k*F_TPB+t)*4);
    }
    __syncthreads();
    for (int bi = 0; bi < F_BTILE; ++bi) {
        int cur = bi & 1; bool more = (bi + 1 < F_BTILE);
        float4 r[4];
        if (more) {
            const float* xrow = x + (size_t)(b0+bi+1) * IDIM;
#pragma unroll
            for (int k = 0; k < 4; ++k)
                r[k] = *reinterpret_cast<const float4*>(xrow + (k*F_TPB+t)*4);
        }
        float res[F_NT];
#pragma unroll
        for (int q = 0; q < F_NT; ++q) {
            float v0 = xsf[cur][ix[q][0]], v1 = xsf[cur][ix[q][1]];
            float v2 = xsf[cur][ix[q][2]], v3 = xsf[cur][ix[q][3]];
            float h0 = fmaf(v3,a[q][1],a[q][0]),  h1 = fmaf(v3,a[q][3],a[q][2]);
            float h2 = fmaf(v3,a[q][5],a[q][4]),  h3 = fmaf(v3,a[q][7],a[q][6]);
            float h4 = fmaf(v3,a[q][9],a[q][8]),  h5 = fmaf(v3,a[q][11],a[q][10]);
            float h6 = fmaf(v3,a[q][13],a[q][12]),h7 = fmaf(v3,a[q][15],a[q][14]);
            float g0 = fmaf(v2,h1,h0), g1 = fmaf(v2,h3,h2);
            float g2 = fmaf(v2,h5,h4), g3 = fmaf(v2,h7,h6);
            res[q] = fmaf(v0, fmaf(v1,g3,g2), fmaf(v1,g1,g0));
        }
        float4 o; o.x=res[0]; o.y=res[1]; o.z=res[2]; o.w=res[3];
        *reinterpret_cast<float4*>(out + (size_t)(b0+bi)*NLUTS + n0) = o;
        if (more) {
            int nxt = cur ^ 1;
#pragma unroll
            for (int k = 0; k < 4; ++k)
                *reinterpret_cast<float4*>(&xsf[nxt][(k*F_TPB+t)*4]) = r[k];
        }
        __syncthreads();
    }
}

extern "C" void kernel_launch(void* const* d_in, const int* in_sizes, int n_in,
                              void* d_out, int out_size, void* d_ws, size_t ws_size,
                              hipStream_t stream) {
    const float* x   = (const float*)d_in[0];
    const float* w   = (const float*)d_in[1];
    const float* wc  = (const float*)d_in[2];
    const int*   idx = (const int*)d_in[3];
    float*       out = (float*)d_out;

    if (ws_size >= (size_t)NLUTS * 16 * sizeof(float)) {
        float* cf = (float*)d_ws;
        coeff_kernel<<<dim3(NLUTS / 64), dim3(64), 0, stream>>>(w, wc, cf);
        lut_main<<<dim3(GRID), dim3(TPB), 0, stream>>>(x, cf, idx, out);
    } else {
        lut_fused<<<dim3(F_GRID), dim3(F_TPB), 0, stream>>>(x, w, wc, idx, out);
    }
}

// Round 7
// 40.044 us; speedup vs baseline: 2.9007x; 1.0379x over previous
//
#include <hip/hip_runtime.h>
#include <hip/hip_fp16.h>
#include <stdint.h>

#define BATCH   1024
#define IDIM    4096
#define NLUTS   16384

// ---- main kernel geometry ----
#define TPB     1024
#define NT      2                  // n's per thread
#define NPB     (TPB * NT)         // 2048
#define NBLK_N  (NLUTS / NPB)      // 8
#define BT      4                  // batch rows per tile (fp16 -> ds_read_b64 gather)
#define TILES   4                  // tiles per block
#define ROWS    (BT * TILES)       // 16 rows per block
#define NBLK_B  (BATCH / ROWS)     // 64
#define GRID    (NBLK_N * NBLK_B)  // 512 = 2 blocks/CU exactly

// ---------------- coefficient pre-kernel ----------------
// a[n][mask]: monomial coefficients of the multilinear form, from
// s = sigmoid(w - wc) reversed + 4-level butterfly (p0,p1)->(p1,p0-p1).
__global__ void coeff_kernel(const float* __restrict__ w,
                             const float* __restrict__ wc,
                             float* __restrict__ cf)
{
    int n = blockIdx.x * 64 + threadIdx.x;   // grid = 256 x 64
    float p[16];
#pragma unroll
    for (int k = 0; k < 4; ++k) {
        float4 wv = *reinterpret_cast<const float4*>(w  + (size_t)n * 16 + 4 * k);
        float4 cv = *reinterpret_cast<const float4*>(wc + (size_t)n * 16 + 4 * k);
        p[15 - (4 * k + 0)] = 1.f / (1.f + __expf(cv.x - wv.x));
        p[15 - (4 * k + 1)] = 1.f / (1.f + __expf(cv.y - wv.y));
        p[15 - (4 * k + 2)] = 1.f / (1.f + __expf(cv.z - wv.z));
        p[15 - (4 * k + 3)] = 1.f / (1.f + __expf(cv.w - wv.w));
    }
#pragma unroll
    for (int s = 8; s >= 1; s >>= 1) {
#pragma unroll
        for (int m = 0; m < 16; ++m) {
            if ((m & s) == 0) { float t0 = p[m]; p[m] = p[m + s]; p[m + s] = t0 - p[m + s]; }
        }
    }
#pragma unroll
    for (int k = 0; k < 4; ++k) {
        float4 o; o.x = p[4*k]; o.y = p[4*k+1]; o.z = p[4*k+2]; o.w = p[4*k+3];
        *reinterpret_cast<float4*>(cf + (size_t)n * 16 + 4 * k) = o;
    }
}

// ---------------- main kernel ----------------
// 1024-thread blocks (the ONLY shape that reached high occupancy: R4 hit 78%
// with 2 blocks/CU co-resident). launch_bounds(1024,2): budget 256 VGPR, so
// the allocator keeps the natural ~60 VGPR (no R4/R5-style 32-VGPR squeeze
// and spill); runtime residency = min(threads:2, LDS:5, VGPR@64:8w) = 2
// blocks = 32 waves/CU.
__global__ __launch_bounds__(TPB, 2)
void lut_main(const float* __restrict__ x,
              const float* __restrict__ cf,
              const int*   __restrict__ indices,
              float* __restrict__ out)
{
    // transposed fp16 tile: xt[col*4 + r] = x[brow+r][col]. 32 KB.
    __shared__ __half xt[IDIM * BT];

    // XCD swizzle: per XCD the 8 n-blocks of one b-range are consecutive
    // -> x rows staged from that XCD's L2, out writes XCD-local.
    int id    = blockIdx.x;
    int xcd   = id & 7;
    int k     = id >> 3;                 // 0..63
    int n_blk = k & (NBLK_N - 1);        // 0..7, fastest
    int b_blk = (k >> 3) * 8 + xcd;      // 0..63, bijective
    int t     = threadIdx.x;
    int n0    = n_blk * NPB + t * NT;
    int b0    = b_blk * ROWS;

    // per-thread LUT indices -> LDS byte offsets (ix*8B per column)
    uint32_t off[NT][4];
#pragma unroll
    for (int i = 0; i < 4; ++i) {
        int2 v = *reinterpret_cast<const int2*>(indices + i * NLUTS + n0);
        off[0][i] = (uint32_t)v.x * 8u;
        off[1][i] = (uint32_t)v.y * 8u;
    }

    // per-thread monomial coefficients (precomputed, 1 MiB, L2-hot)
    float a[NT][16];
#pragma unroll
    for (int q = 0; q < NT; ++q) {
#pragma unroll
        for (int kk = 0; kk < 4; ++kk) {
            float4 v = *reinterpret_cast<const float4*>(cf + (size_t)(n0 + q) * 16 + 4 * kk);
            a[q][4*kk] = v.x; a[q][4*kk+1] = v.y; a[q][4*kk+2] = v.z; a[q][4*kk+3] = v.w;
        }
    }

    const char* xt_bytes = reinterpret_cast<const char*>(xt);

#pragma unroll 1
    for (int g = 0; g < TILES; ++g) {
        if (g) __syncthreads();            // previous tile's reads complete

        // ---- stage tile g: thread owns col pairs p = t + 1024*h, h=0..1 ----
        // global: float2 loads, consecutive lanes contiguous per (h,row).
        // LDS: ds_write_b128 at byte p*16 -> consecutive lanes cover all 32
        // banks -> conflict-free.
        {
            const float* xb = x + (size_t)(b0 + g * BT) * IDIM;
#pragma unroll
            for (int h = 0; h < 2; ++h) {
                int p = h * TPB + t;
                int c = 2 * p;
                float2 r0 = *reinterpret_cast<const float2*>(xb + 0 * IDIM + c);
                float2 r1 = *reinterpret_cast<const float2*>(xb + 1 * IDIM + c);
                float2 r2 = *reinterpret_cast<const float2*>(xb + 2 * IDIM + c);
                float2 r3 = *reinterpret_cast<const float2*>(xb + 3 * IDIM + c);
                __half2 c0a = __floats2half2_rn(r0.x, r1.x);   // col c   rows 0,1
                __half2 c0b = __floats2half2_rn(r2.x, r3.x);   // col c   rows 2,3
                __half2 c1a = __floats2half2_rn(r0.y, r1.y);   // col c+1 rows 0,1
                __half2 c1b = __floats2half2_rn(r2.y, r3.y);   // col c+1 rows 2,3
                uint4 v;
                v.x = *reinterpret_cast<uint32_t*>(&c0a);
                v.y = *reinterpret_cast<uint32_t*>(&c0b);
                v.z = *reinterpret_cast<uint32_t*>(&c1a);
                v.w = *reinterpret_cast<uint32_t*>(&c1b);
                *reinterpret_cast<uint4*>(&xt[(size_t)c * 4]) = v;
            }
        }
        __syncthreads();                   // tile visible to all waves

        // ---- compute: per q, 4 x ds_read_b64 gathers (4 rows each) ----
        float res[NT][BT];
#pragma unroll
        for (int q = 0; q < NT; ++q) {
            uint2 gld[4];
#pragma unroll
            for (int i = 0; i < 4; ++i)
                gld[i] = *reinterpret_cast<const uint2*>(xt_bytes + off[q][i]);

            // convert each gathered column ONCE: c[i][r] = x[row r][col i]
            float c[4][4];
#pragma unroll
            for (int i = 0; i < 4; ++i) {
                __half2 h01 = *reinterpret_cast<__half2*>(&gld[i].x);
                __half2 h23 = *reinterpret_cast<__half2*>(&gld[i].y);
                float2 f01 = __half22float2(h01);
                float2 f23 = __half22float2(h23);
                c[i][0] = f01.x; c[i][1] = f01.y; c[i][2] = f23.x; c[i][3] = f23.y;
            }
#pragma unroll
            for (int r = 0; r < BT; ++r) {
                float v0 = c[0][r], v1 = c[1][r], v2 = c[2][r], v3 = c[3][r];
                float h0 = fmaf(v3, a[q][1],  a[q][0]);
                float h1 = fmaf(v3, a[q][3],  a[q][2]);
                float h2 = fmaf(v3, a[q][5],  a[q][4]);
                float h3 = fmaf(v3, a[q][7],  a[q][6]);
                float h4 = fmaf(v3, a[q][9],  a[q][8]);
                float h5 = fmaf(v3, a[q][11], a[q][10]);
                float h6 = fmaf(v3, a[q][13], a[q][12]);
                float h7 = fmaf(v3, a[q][15], a[q][14]);
                float g0 = fmaf(v2, h1, h0);
                float g1 = fmaf(v2, h3, h2);
                float g2 = fmaf(v2, h5, h4);
                float g3 = fmaf(v2, h7, h6);
                float f0 = fmaf(v1, g1, g0);
                float f1 = fmaf(v1, g3, g2);
                res[q][r] = fmaf(v0, f1, f0);
            }
        }

        // coalesced float2 stores: 4 rows x (2 consecutive n per thread)
#pragma unroll
        for (int r = 0; r < BT; ++r) {
            float2 o; o.x = res[0][r]; o.y = res[1][r];
            *reinterpret_cast<float2*>(out + (size_t)(b0 + g * BT + r) * NLUTS + n0) = o;
        }
    }
}

// ---------------- fallback (round-1 fused kernel, used only if ws too small) ----------------
#define F_TPB   256
#define F_NT    4
#define F_NPB   (F_TPB * F_NT)
#define F_NBLKN (NLUTS / F_NPB)
#define F_BTILE 16
#define F_GRID  (F_NBLKN * (BATCH / F_BTILE))

__global__ __launch_bounds__(F_TPB, 4)
void lut_fused(const float* __restrict__ x, const float* __restrict__ w,
               const float* __restrict__ wcomp, const int* __restrict__ indices,
               float* __restrict__ out)
{
    __shared__ float xsf[2][IDIM];
    int id = blockIdx.x;
    int swz = (id & 7) * (F_GRID / 8) + (id >> 3);
    int b_blk = swz / F_NBLKN, n_blk = swz % F_NBLKN;
    int t = threadIdx.x;
    int n0 = n_blk * F_NPB + t * F_NT;
    int b0 = b_blk * F_BTILE;
    int ix[F_NT][4];
#pragma unroll
    for (int i = 0; i < 4; ++i) {
        int4 v = *reinterpret_cast<const int4*>(indices + i * NLUTS + n0);
        ix[0][i] = v.x; ix[1][i] = v.y; ix[2][i] = v.z; ix[3][i] = v.w;
    }
    float a[F_NT][16];
#pragma unroll
    for (int q = 0; q < F_NT; ++q) {
        int n = n0 + q; float p[16];
#pragma unroll
        for (int k = 0; k < 4; ++k) {
            float4 wv = *reinterpret_cast<const float4*>(w     + (size_t)n * 16 + k * 4);
            float4 cv = *reinterpret_cast<const float4*>(wcomp + (size_t)n * 16 + k * 4);
            p[15-(4*k+0)] = 1.f/(1.f+__expf(cv.x-wv.x));
            p[15-(4*k+1)] = 1.f/(1.f+__expf(cv.y-wv.y));
            p[15-(4*k+2)] = 1.f/(1.f+__expf(cv.z-wv.z));
            p[15-(4*k+3)] = 1.f/(1.f+__expf(cv.w-wv.w));
        }
#pragma unroll
        for (int s = 8; s >= 1; s >>= 1)
#pragma unroll
            for (int m = 0; m < 16; ++m)
                if ((m & s) == 0) { float t0 = p[m]; p[m] = p[m+s]; p[m+s] = t0 - p[m+s]; }
#pragma unroll
        for (int m = 0; m < 16; ++m) a[q][m] = p[m];
    }
    {
        const float* xrow = x + (size_t)b0 * IDIM;
#pragma unroll
        for (int k = 0; k < 4; ++k)
            *reinterpret_cast<float4*>(&xsf[0][(k*F_TPB+t)*4]) =
                *reinterpret_cast<const float4*>(xrow + (k*F_TPB+t)*4);
    }
    __syncthreads();
    for (int bi = 0; bi < F_BTILE; ++bi) {
        int cur = bi & 1; bool more = (bi + 1 < F_BTILE);
        float4 r[4];
        if (more) {
            const float* xrow = x + (size_t)(b0+bi+1) * IDIM;
#pragma unroll
            for (int k = 0; k < 4; ++k)
                r[k] = *reinterpret_cast<const float4*>(xrow + (k*F_TPB+t)*4);
        }
        float res[F_NT];
#pragma unroll
        for (int q = 0; q < F_NT; ++q) {
            float v0 = xsf[cur][ix[q][0]], v1 = xsf[cur][ix[q][1]];
            float v2 = xsf[cur][ix[q][2]], v3 = xsf[cur][ix[q][3]];
            float h0 = fmaf(v3,a[q][1],a[q][0]),  h1 = fmaf(v3,a[q][3],a[q][2]);
            float h2 = fmaf(v3,a[q][5],a[q][4]),  h3 = fmaf(v3,a[q][7],a[q][6]);
            float h4 = fmaf(v3,a[q][9],a[q][8]),  h5 = fmaf(v3,a[q][11],a[q][10]);
            float h6 = fmaf(v3,a[q][13],a[q][12]),h7 = fmaf(v3,a[q][15],a[q][14]);
            float g0 = fmaf(v2,h1,h0), g1 = fmaf(v2,h3,h2);
            float g2 = fmaf(v2,h5,h4), g3 = fmaf(v2,h7,h6);
            res[q] = fmaf(v0, fmaf(v1,g3,g2), fmaf(v1,g1,g0));
        }
        float4 o; o.x=res[0]; o.y=res[1]; o.z=res[2]; o.w=res[3];
        *reinterpret_cast<float4*>(out + (size_t)(b0+bi)*NLUTS + n0) = o;
        if (more) {
            int nxt = cur ^ 1;
#pragma unroll
            for (int k = 0; k < 4; ++k)
                *reinterpret_cast<float4*>(&xsf[nxt][(k*F_TPB+t)*4]) = r[k];
        }
        __syncthreads();
    }
}

extern "C" void kernel_launch(void* const* d_in, const int* in_sizes, int n_in,
                              void* d_out, int out_size, void* d_ws, size_t ws_size,
                              hipStream_t stream) {
    const float* x   = (const float*)d_in[0];
    const float* w   = (const float*)d_in[1];
    const float* wc  = (const float*)d_in[2];
    const int*   idx = (const int*)d_in[3];
    float*       out = (float*)d_out;

    if (ws_size >= (size_t)NLUTS * 16 * sizeof(float)) {
        float* cf = (float*)d_ws;
        coeff_kernel<<<dim3(NLUTS / 64), dim3(64), 0, stream>>>(w, wc, cf);
        lut_main<<<dim3(GRID), dim3(TPB), 0, stream>>>(x, cf, idx, out);
    } else {
        lut_fused<<<dim3(F_GRID), dim3(F_TPB), 0, stream>>>(x, w, wc, idx, out);
    }
}